// Round 5
// baseline (153.666 us; speedup 1.0000x reference)
//
#include <hip/hip_runtime.h>
#include <hip/hip_bf16.h>
#include <math.h>

// Problem constants
#define BQ 128
#define PP 256
#define MQ 16
#define MP 32
#define DD 768
#define MROWS (BQ*MQ)   // 2048
#define NROWS (PP*MP)   // 8192

typedef float f32x4 __attribute__((ext_vector_type(4)));
typedef int   i32x4 __attribute__((ext_vector_type(4)));

// ---------- fp32 -> fp8 e4m3 + k-shuffle, both tensors, one launch ----------
// Within each 64-k block, 16B chunk c holds k-groups {c, c+4}. One
// ds_read_b128 feeds TWO 16x16x32 MFMAs (k and k+32). Also zero-inits
// loss_out[0] (stream-ordered before loss_kernel).
#define NQG (MROWS*96)   // 196608 groups of 8
#define NPG (NROWS*96)   // 786432

__global__ void conv_fp8_both(const float4* __restrict__ q, const float4* __restrict__ p,
                              unsigned char* __restrict__ qb, unsigned char* __restrict__ pb,
                              float* __restrict__ loss_out) {
    int idx = blockIdx.x * blockDim.x + threadIdx.x;
    if (idx == 0) loss_out[0] = 0.f;
    const float4* in; unsigned char* out; int i;
    if (idx < NQG) { in = q; out = qb; i = idx; }
    else           { in = p; out = pb; i = idx - NQG; }
    float4 x0 = in[2 * i];
    float4 x1 = in[2 * i + 1];
    int lo = 0, hi = 0;
    lo = __builtin_amdgcn_cvt_pk_fp8_f32(x0.x, x0.y, lo, false);
    lo = __builtin_amdgcn_cvt_pk_fp8_f32(x0.z, x0.w, lo, true);
    hi = __builtin_amdgcn_cvt_pk_fp8_f32(x1.x, x1.y, hi, false);
    hi = __builtin_amdgcn_cvt_pk_fp8_f32(x1.z, x1.w, hi, true);
    int row = i / 96;
    int g96 = i - row * 96;
    int blk = g96 >> 3, g = g96 & 7;
    int dstoff = (g < 4) ? (g * 16) : ((g - 4) * 16 + 8);
    *(uint2*)(out + (size_t)row * DD + blk * 64 + dstoff) = make_uint2((unsigned)lo, (unsigned)hi);
}

// ---------- DPP wave-64 f32 reduction (pure VALU) ----------
__device__ inline float dpp_reduce_f32(float x) {
    int m;
    m = __builtin_amdgcn_update_dpp(0, __float_as_int(x), 0x111, 0xF, 0xF, true); x += __int_as_float(m);
    m = __builtin_amdgcn_update_dpp(0, __float_as_int(x), 0x112, 0xF, 0xF, true); x += __int_as_float(m);
    m = __builtin_amdgcn_update_dpp(0, __float_as_int(x), 0x114, 0xF, 0xF, true); x += __int_as_float(m);
    m = __builtin_amdgcn_update_dpp(0, __float_as_int(x), 0x118, 0xF, 0xF, true); x += __int_as_float(m);
    m = __builtin_amdgcn_update_dpp(0, __float_as_int(x), 0x142, 0xA, 0xF, true); x += __int_as_float(m);
    m = __builtin_amdgcn_update_dpp(0, __float_as_int(x), 0x143, 0xC, 0xF, true); x += __int_as_float(m);
    return x;   // lane 63 = total
}

// ---------- fused fp8 GEMM (256x256, ring-4, counted vmcnt) + select --------
// R5: the structural fix. R0-R4 all used __syncthreads() per K-iter, which
// drains vmcnt(0) INCLUDING the just-issued prefetch -> full staging latency
// exposed every iter (MfmaUtil pinned 14-17%). This round:
//  - 256x256 tile, 512 thr (8 waves 2Mx4N, wave tile 128x64), BK=64.
//  - ring-4 LDS (4 x 32 KB = 128 KB dynamic), grid 32x8=256 = 1 block/CU.
//  - counted vmcnt: stage tile t+3 each iter; before reading tile t wait
//    vmcnt(8) (= tiles t+1,t+2 in flight ACROSS the barrier; never 0 in
//    the main loop). One s_barrier per K-tile (slot being staged is always
//    disjoint from slots being read; prior slot provably drained: its
//    ds_reads were consumed by MFMAs before the barrier).
//  - asm ds_read_b128 + lgkmcnt(0) + sched_barrier(0) (guide rule #18), so
//    the compiler cannot insert a conservative vmcnt(0) nor hoist MFMAs.
//  - setprio(1) around the MFMA cluster (T5; role-split exists here).
//  - no forced min-waves: ~200 unified regs at 2 waves/SIMD, no spills.
// Accumulation order per acc element (tile 0..11, lo then hi) is bitwise
// IDENTICAL to R0-R4 -> absmax must reproduce 96.0.
#define BM 256
#define BN 256
#define BK 64
#define KIT (DD / BK)        // 12
#define SLOT_BYTES 32768     // A 16 KB + B 16 KB per K-tile slot
#define A_OFF 0
#define B_OFF 16384

__device__ inline void load16_to_lds(const unsigned char* g, unsigned char* l) {
    __builtin_amdgcn_global_load_lds(
        (const __attribute__((address_space(1))) unsigned int*)(g),
        (__attribute__((address_space(3))) unsigned int*)(l),
        16, 0, 0);
}

__device__ inline unsigned lds_off(const unsigned char* p) {
    return (unsigned)(unsigned long long)
        (const __attribute__((address_space(3))) unsigned char*)p;
}

__device__ inline i32x4 ds_read_b128a(unsigned addr) {
    i32x4 d;
    asm volatile("ds_read_b128 %0, %1" : "=v"(d) : "v"(addr));
    return d;
}

__device__ inline float softplus_f(float x) {
    return (x > 20.f) ? x : log1pf(expf(x));
}

__device__ inline long lo64(i32x4 v) {
    return (long)(((unsigned long)(unsigned)v[1] << 32) | (unsigned)v[0]);
}
__device__ inline long hi64(i32x4 v) {
    return (long)(((unsigned long)(unsigned)v[3] << 32) | (unsigned)v[2]);
}

__global__ __launch_bounds__(512) void gemm_select(const unsigned char* __restrict__ A,
                                                   const unsigned char* __restrict__ B,
                                                   const int* __restrict__ qm,
                                                   const int* __restrict__ pm,
                                                   const float* __restrict__ araw,
                                                   const float* __restrict__ braw,
                                                   float* __restrict__ logits) {
    extern __shared__ __align__(16) unsigned char smem[];   // 4 x 32 KB ring

    const int tid  = threadIdx.x;
    const int lane = tid & 63;
    const int wid  = tid >> 6;        // 8 waves: 2 (row halves) x 4 (col quads)
    const int wr   = wid >> 2;        // 0..1 -> rows wr*128..+128
    const int wc   = wid & 3;         // 0..3 -> cols wc*64..+64
    const int tileM = blockIdx.y * BM;
    const int tileN = blockIdx.x * BN;
    const int bBase = blockIdx.y * 16;  // 16 q-groups per tile
    const int pBase = blockIdx.x * 8;   // 8 p-groups per tile

    // ---- accumulators: 8 row-blocks x 4 col-blocks of 16x16 (128 AGPR)
    f32x4 acc[8][4];
    #pragma unroll
    for (int i = 0; i < 8; ++i)
        #pragma unroll
        for (int j = 0; j < 4; ++j) {
            f32x4 z = {0.f, 0.f, 0.f, 0.f};
            acc[i][j] = z;
        }

    // ---- staging: per K-tile 4 halves (A-lo/A-hi/B-lo/B-hi), each 128 rows
    // x 64 B = 1 load per thread. global chunk = l2 ^ sigma(row) (involution),
    // LDS linear. Wave w stages rows w*16..+16 of each half.
    const int srow = tid >> 2;                        // 0..127
    const int chunkoff = (((tid & 3) ^ ((tid >> 3) & 3)) << 4);
    const unsigned char* ga0 = A + (size_t)(tileM + srow) * DD + chunkoff;
    const unsigned char* ga1 = ga0 + (size_t)128 * DD;
    const unsigned char* gb0 = B + (size_t)(tileN + srow) * DD + chunkoff;
    const unsigned char* gb1 = gb0 + (size_t)128 * DD;
    const int ldsw = wid * 1024;                      // wave-uniform

    // ---- read side: logical chunk q of row r lives at slot q ^ ((r>>1)&3)
    const int r0 = lane & 15;
    const int qq = lane >> 4;
    const int slotq = ((qq ^ ((r0 >> 1) & 3)) << 4);
    const int abase = A_OFF + (wr * 128 + r0) * 64 + slotq;   // + mi*1024
    const int bbase = B_OFF + (wc * 64  + r0) * 64 + slotq;   // + ni*1024
    const unsigned lds0 = lds_off(smem);

    // ---- prologue: stage K-tiles 0,1,2 into slots 0,1,2 (12 loads/thread grp)
    for (int t = 0; t < 3; ++t) {
        unsigned char* sb = smem + t * SLOT_BYTES;
        load16_to_lds(ga0, sb + A_OFF + ldsw);
        load16_to_lds(ga1, sb + A_OFF + 8192 + ldsw);
        load16_to_lds(gb0, sb + B_OFF + ldsw);
        load16_to_lds(gb1, sb + B_OFF + 8192 + ldsw);
        ga0 += BK; ga1 += BK; gb0 += BK; gb1 += BK;
    }

    // ---- main loop: counted vmcnt, one barrier per K-tile, never drain
    for (int t = 0; t < KIT; ++t) {
        if (t < KIT - 2)       asm volatile("s_waitcnt vmcnt(8)" ::: "memory");
        else if (t == KIT - 2) asm volatile("s_waitcnt vmcnt(4)" ::: "memory");
        else                   asm volatile("s_waitcnt vmcnt(0)" ::: "memory");
        __builtin_amdgcn_s_barrier();

        if (t + 3 < KIT) {   // stage tile t+3 into slot (t+3)&3 (disjoint)
            unsigned char* sb = smem + ((t + 3) & 3) * SLOT_BYTES;
            load16_to_lds(ga0, sb + A_OFF + ldsw);
            load16_to_lds(ga1, sb + A_OFF + 8192 + ldsw);
            load16_to_lds(gb0, sb + B_OFF + ldsw);
            load16_to_lds(gb1, sb + B_OFF + 8192 + ldsw);
            ga0 += BK; ga1 += BK; gb0 += BK; gb1 += BK;
        }

        const unsigned sbase = lds0 + (unsigned)((t & 3) * SLOT_BYTES);
        i32x4 af[8], bf[4];
        #pragma unroll
        for (int mi = 0; mi < 8; ++mi)
            af[mi] = ds_read_b128a(sbase + abase + mi * 1024);
        #pragma unroll
        for (int ni = 0; ni < 4; ++ni)
            bf[ni] = ds_read_b128a(sbase + bbase + ni * 1024);
        asm volatile("s_waitcnt lgkmcnt(0)" ::: "memory");
        __builtin_amdgcn_sched_barrier(0);

        __builtin_amdgcn_s_setprio(1);
        #pragma unroll
        for (int mi = 0; mi < 8; ++mi)
            #pragma unroll
            for (int ni = 0; ni < 4; ++ni) {
                acc[mi][ni] = __builtin_amdgcn_mfma_f32_16x16x32_fp8_fp8(lo64(af[mi]), lo64(bf[ni]), acc[mi][ni], 0, 0, 0);
                acc[mi][ni] = __builtin_amdgcn_mfma_f32_16x16x32_fp8_fp8(hi64(af[mi]), hi64(bf[ni]), acc[mi][ni], 0, 0, 0);
            }
        __builtin_amdgcn_s_setprio(0);
    }

    // ---- p-group masks for this wave's 2 col groups
    unsigned pw0, pw1; int np0, np1;
    {
        bool v0 = (lane < MP) && (pm[(pBase + wc * 2 + 0) * MP + lane] != 0);
        unsigned long long b0 = __ballot(v0);
        pw0 = (unsigned)b0; np0 = __popcll(b0);
        bool v1 = (lane < MP) && (pm[(pBase + wc * 2 + 1) * MP + lane] != 0);
        unsigned long long b1 = __ballot(v1);
        pw1 = (unsigned)b1; np1 = __popcll(b1);
    }

    // ---- selection: 16 logits/wave (8 q-groups x 2 p-groups)
    // C/D layout (m89): row=(lane>>4)*4+(t&3), col=(t>>2)*16+(lane&15)
    float aco = softplus_f(araw[0]);
    float bco = softplus_f(braw[0]);
    const int rowb = (lane >> 4) * 4;
    const int colb = lane & 15;

    #pragma unroll 1
    for (int g = 0; g < 8; ++g) {
        f32x4 a0, a1, a2, a3;
        switch (g) {   // static acc indexing (rule #20)
        case 0:  a0 = acc[0][0]; a1 = acc[0][1]; a2 = acc[0][2]; a3 = acc[0][3]; break;
        case 1:  a0 = acc[1][0]; a1 = acc[1][1]; a2 = acc[1][2]; a3 = acc[1][3]; break;
        case 2:  a0 = acc[2][0]; a1 = acc[2][1]; a2 = acc[2][2]; a3 = acc[2][3]; break;
        case 3:  a0 = acc[3][0]; a1 = acc[3][1]; a2 = acc[3][2]; a3 = acc[3][3]; break;
        case 4:  a0 = acc[4][0]; a1 = acc[4][1]; a2 = acc[4][2]; a3 = acc[4][3]; break;
        case 5:  a0 = acc[5][0]; a1 = acc[5][1]; a2 = acc[5][2]; a3 = acc[5][3]; break;
        case 6:  a0 = acc[6][0]; a1 = acc[6][1]; a2 = acc[6][2]; a3 = acc[6][3]; break;
        default: a0 = acc[7][0]; a1 = acc[7][1]; a2 = acc[7][2]; a3 = acc[7][3]; break;
        }
        bool vq = (lane < MQ) && (qm[(bBase + wr * 8 + g) * MQ + lane] != 0);
        unsigned long long qb_ = __ballot(vq);
        unsigned qwv = (unsigned)qb_;
        int nqv = __popcll(qb_);

        #pragma unroll 1
        for (int h = 0; h < 2; ++h) {
            f32x4 w0 = h ? a2 : a0;
            f32x4 w1 = h ? a3 : a1;
            unsigned pwv = h ? pw1 : pw0;
            int npv = h ? np1 : np0;

            int n  = nqv * npv;               // >= 1
            int k  = (4 * n) / 10; if (k < 1) k = 1;
            int m2 = n - (8 * n) / 10;        // complement rank, >= 1

            float v[8] = {w0[0], w0[1], w0[2], w0[3], w1[0], w1[1], w1[2], w1[3]};
            int key[8];
            float tot = 0.f;
            #pragma unroll
            for (int t = 0; t < 8; ++t) {
                int row = rowb + (t & 3);
                int col = (t >> 2) * 16 + colb;
                int kf = (int)floorf(v[t] * 2.0f) + 512;     // monotone, |v| << 256
                kf = min(max(kf, 1), 1023);                  // v_med3_i32
                bool val = (((qwv >> row) & 1u) != 0u) && (((pwv >> col) & 1u) != 0u);
                key[t] = val ? kf : 0;                       // valid >= 1
                if (val) tot += v[t];
            }

            // dual 10-bit MSB-first radix descent: ballot -> s_bcnt1_b64 on
            // the scalar pipe; thresholds wave-uniform, no DPP, no readlane.
            int T1 = 0, T2 = 0;
            for (int bit = 9; bit >= 0; --bit) {
                int c1 = T1 | (1 << bit);
                int c2 = T2 | (1 << bit);
                int cnt1 = 0, cnt2 = 0;
                #pragma unroll
                for (int t = 0; t < 8; ++t) {
                    cnt1 += __popcll(__ballot(key[t] >= c1));
                    cnt2 += __popcll(__ballot(key[t] >= c2));
                }
                if (cnt1 >= k)  T1 = c1;
                if (cnt2 >= m2) T2 = c2;
            }

            // tie-corrected sums: f32 via DPP (lane 63), counts via ballot
            float S1 = 0.f, S2 = 0.f;
            int c1n = 0, c2n = 0;
            #pragma unroll
            for (int t = 0; t < 8; ++t) {
                bool g1 = key[t] > T1;
                bool g2 = key[t] > T2;
                if (g1) S1 += v[t];
                if (g2) S2 += v[t];
                c1n += __popcll(__ballot(g1));
                c2n += __popcll(__ballot(g2));
            }
            S1  = dpp_reduce_f32(S1);
            S2  = dpp_reduce_f32(S2);
            tot = dpp_reduce_f32(tot);

            if (lane == 63) {
                float f1 = 0.5f * (float)(T1 - 512);   // tie-bucket lower edge
                float f2 = 0.5f * (float)(T2 - 512);
                float top = S1 + (float)(k  - c1n) * f1;
                float cmp = S2 + (float)(m2 - c2n) * f2;
                float bot = tot - cmp;
                logits[(bBase + wr * 8 + g) * PP + (pBase + wc * 2 + h)] = aco * top - bco * bot;
            }
        }
    }
}

// ---------- loss = mean_b (lse(logits[b,:]) - logits[b,b]) ----------
// 32 blocks x 4 waves, one row per wave, atomicAdd partials (out[0] zeroed
// by conv_fp8_both, stream-ordered).
__global__ __launch_bounds__(256) void loss_kernel(const float* __restrict__ logits,
                                                   float* __restrict__ loss_out) {
    const int lane = threadIdx.x & 63;
    const int wid  = threadIdx.x >> 6;
    const int r = blockIdx.x * 4 + wid;
    const float* row = logits + r * PP;
    float x0 = row[lane], x1 = row[lane + 64], x2 = row[lane + 128], x3 = row[lane + 192];
    float m = fmaxf(fmaxf(x0, x1), fmaxf(x2, x3));
    #pragma unroll
    for (int off = 32; off > 0; off >>= 1)
        m = fmaxf(m, __shfl_xor(m, off, 64));
    float s = expf(x0 - m) + expf(x1 - m) + expf(x2 - m) + expf(x3 - m);
    #pragma unroll
    for (int off = 32; off > 0; off >>= 1)
        s += __shfl_xor(s, off, 64);
    if (lane == 0)
        atomicAdd(loss_out, (m + logf(s) - row[r]) * (1.0f / (float)BQ));
}

extern "C" void kernel_launch(void* const* d_in, const int* in_sizes, int n_in,
                              void* d_out, int out_size, void* d_ws, size_t ws_size,
                              hipStream_t stream) {
    const float* q  = (const float*)d_in[0];
    const float* pe = (const float*)d_in[1];
    const int*   qm = (const int*)d_in[2];
    const int*   pm = (const int*)d_in[3];
    const float* ar = (const float*)d_in[4];
    const float* br = (const float*)d_in[5];
    float* out = (float*)d_out;           // [0] = loss, [1..32768] = logits

    // workspace: qb (1.5 MB fp8, k-shuffled) | pb (6 MB fp8, k-shuffled)
    char* ws = (char*)d_ws;
    unsigned char* qb = (unsigned char*)ws;
    unsigned char* pb = (unsigned char*)(ws + (size_t)MROWS * DD);

    // 1) convert fp32 -> fp8 e4m3 with k-shuffle (+ zero loss accumulator)
    conv_fp8_both<<<(NQG + NPG) / 256, 256, 0, stream>>>(
        (const float4*)q, (const float4*)pe, qb, pb, out);

    // 2) fused fp8 sim-GEMM + dual top-k -> logits
    // 256x256 tile, ring-4 128 KB dynamic LDS; grid 256 = exactly 1 block/CU
    dim3 gg(NROWS / BN, MROWS / BM, 1);   // (32, 8) = 256 blocks
    gemm_select<<<gg, 512, 4 * SLOT_BYTES, stream>>>(qb, pb, qm, pm, ar, br, out + 1);

    // 3) loss (parallel, atomic accumulate)
    loss_kernel<<<32, 256, 0, stream>>>(out + 1, out);
}

// Round 7
// 136.538 us; speedup vs baseline: 1.1254x; 1.1254x over previous
//
#include <hip/hip_runtime.h>
#include <hip/hip_bf16.h>
#include <math.h>

// Problem constants
#define BQ 128
#define PP 256
#define MQ 16
#define MP 32
#define DD 768
#define MROWS (BQ*MQ)   // 2048
#define NROWS (PP*MP)   // 8192

typedef float f32x4 __attribute__((ext_vector_type(4)));

// ---------- fp32 -> fp8 e4m3 + k-shuffle, both tensors, one launch ----------
// Within each 64-k block, 16B chunk c holds k-groups {c, c+4}. One
// ds_read_b128 feeds TWO 16x16x32 MFMAs (k and k+32). Also zero-inits
// loss_out[0] (stream-ordered before loss_kernel).
#define NQG (MROWS*96)   // 196608 groups of 8
#define NPG (NROWS*96)   // 786432

__global__ void conv_fp8_both(const float4* __restrict__ q, const float4* __restrict__ p,
                              unsigned char* __restrict__ qb, unsigned char* __restrict__ pb,
                              float* __restrict__ loss_out) {
    int idx = blockIdx.x * blockDim.x + threadIdx.x;
    if (idx == 0) loss_out[0] = 0.f;
    const float4* in; unsigned char* out; int i;
    if (idx < NQG) { in = q; out = qb; i = idx; }
    else           { in = p; out = pb; i = idx - NQG; }
    float4 x0 = in[2 * i];
    float4 x1 = in[2 * i + 1];
    int lo = 0, hi = 0;
    lo = __builtin_amdgcn_cvt_pk_fp8_f32(x0.x, x0.y, lo, false);
    lo = __builtin_amdgcn_cvt_pk_fp8_f32(x0.z, x0.w, lo, true);
    hi = __builtin_amdgcn_cvt_pk_fp8_f32(x1.x, x1.y, hi, false);
    hi = __builtin_amdgcn_cvt_pk_fp8_f32(x1.z, x1.w, hi, true);
    int row = i / 96;
    int g96 = i - row * 96;
    int blk = g96 >> 3, g = g96 & 7;
    int dstoff = (g < 4) ? (g * 16) : ((g - 4) * 16 + 8);
    *(uint2*)(out + (size_t)row * DD + blk * 64 + dstoff) = make_uint2((unsigned)lo, (unsigned)hi);
}

// ---------- DPP wave-64 f32 reduction (pure VALU) ----------
__device__ inline float dpp_reduce_f32(float x) {
    int m;
    m = __builtin_amdgcn_update_dpp(0, __float_as_int(x), 0x111, 0xF, 0xF, true); x += __int_as_float(m);
    m = __builtin_amdgcn_update_dpp(0, __float_as_int(x), 0x112, 0xF, 0xF, true); x += __int_as_float(m);
    m = __builtin_amdgcn_update_dpp(0, __float_as_int(x), 0x114, 0xF, 0xF, true); x += __int_as_float(m);
    m = __builtin_amdgcn_update_dpp(0, __float_as_int(x), 0x118, 0xF, 0xF, true); x += __int_as_float(m);
    m = __builtin_amdgcn_update_dpp(0, __float_as_int(x), 0x142, 0xA, 0xF, true); x += __int_as_float(m);
    m = __builtin_amdgcn_update_dpp(0, __float_as_int(x), 0x143, 0xC, 0xF, true); x += __int_as_float(m);
    return x;   // lane 63 = total
}

// ---------- fused fp8 GEMM (64x128, BK=64) + register-resident selection -----
// R7 = R6 resubmitted verbatim (second infra failure; R3 resubmit precedent).
// R6 rationale: revert to the measured-best R1 structure (55 us) minus its
// one measured defect. Evidence R0-R5: high blocks/CU TLP beats every
// pipelining scheme here (R2 dbuf 58, R5 ring-4+vmcnt 75 vs R1 simple 55).
// R1's defect: (256,8) forced a 64-VGPR budget -> VGPR_Count 32, 10.6 MB
// scratch spills. Fix: (256,4) = 128-reg budget >= ~90 actually needed ->
// no spills, exactly 4 blocks/CU, grid 2048 = two clean uniform rounds.
// Masks loaded AFTER the K-loop (not live across it).
// Accumulation order per acc element is bitwise IDENTICAL to R0-R5.
#define BM 64
#define BN 128
#define BK 64
#define KIT (DD / BK)   // 12

__device__ inline void load16_to_lds(const unsigned char* g, unsigned char* l) {
    __builtin_amdgcn_global_load_lds(
        (const __attribute__((address_space(1))) unsigned int*)(g),
        (__attribute__((address_space(3))) unsigned int*)(l),
        16, 0, 0);
}

__device__ inline float softplus_f(float x) {
    return (x > 20.f) ? x : log1pf(expf(x));
}

__device__ inline long lo64(int4 v) {
    return (long)(((unsigned long)(unsigned)v.y << 32) | (unsigned)v.x);
}
__device__ inline long hi64(int4 v) {
    return (long)(((unsigned long)(unsigned)v.w << 32) | (unsigned)v.z);
}

__global__ __launch_bounds__(256, 4) void gemm_select(const unsigned char* __restrict__ A,
                                                      const unsigned char* __restrict__ B,
                                                      const int* __restrict__ qm,
                                                      const int* __restrict__ pm,
                                                      const float* __restrict__ araw,
                                                      const float* __restrict__ braw,
                                                      float* __restrict__ logits) {
    __shared__ __align__(16) unsigned char sA[BM * BK];   // 4 KB
    __shared__ __align__(16) unsigned char sB[BN * BK];   // 8 KB

    const int tid  = threadIdx.x;
    const int lane = tid & 63;
    const int wid  = tid >> 6;        // 4 waves, 2x2 over 64x128
    const int wr   = wid >> 1;
    const int wc   = wid & 1;
    const int tileM = blockIdx.y * BM;
    const int tileN = blockIdx.x * BN;
    const int bBase = blockIdx.y * 4;
    const int pBase = blockIdx.x * 4;

    // ---- GEMM phase (fp8, BK=64)
    f32x4 acc[2][4];
    #pragma unroll
    for (int i = 0; i < 2; ++i)
        #pragma unroll
        for (int j = 0; j < 4; ++j) {
            f32x4 z = {0.f, 0.f, 0.f, 0.f};
            acc[i][j] = z;
        }

    // staging: 3 x 16B per thread per iter. 4 lanes per 64B row.
    // global column chunk fetched = l2 ^ sigma(row); LDS linear,
    // so slot s holds logical chunk s ^ sigma(row) (involution).
    const int lr = lane >> 2, l2 = lane & 3;
    const int sg = (lr >> 1) & 3;                    // sigma(row): row%16 = lr
    const int rowA  = wid * 16 + lr;                 // A rows 0..63
    const int rowB0 = wid * 16 + lr;                 // B rows 0..63
    const int rowB1 = 64 + wid * 16 + lr;            // B rows 64..127
    const unsigned char* pa  = A + (size_t)(tileM + rowA ) * DD + ((l2 ^ sg) << 4);
    const unsigned char* pb0 = B + (size_t)(tileN + rowB0) * DD + ((l2 ^ sg) << 4);
    const unsigned char* pb1 = B + (size_t)(tileN + rowB1) * DD + ((l2 ^ sg) << 4);
    unsigned char* dA  = &sA[wid * 16 * BK];
    unsigned char* dB0 = &sB[wid * 16 * BK];
    unsigned char* dB1 = &sB[(4 + wid) * 16 * BK];

    // read side: logical chunk q of row r lives at slot q ^ ((r>>1)&3)
    const int r0 = lane & 15;
    const int q  = lane >> 4;
    const int slotq = ((q ^ ((r0 >> 1) & 3)) << 4);
    int aoff[2], boff[4];
    #pragma unroll
    for (int mi = 0; mi < 2; ++mi)
        aoff[mi] = (wr * 32 + mi * 16 + r0) * BK + slotq;
    #pragma unroll
    for (int ni = 0; ni < 4; ++ni)
        boff[ni] = (wc * 64 + ni * 16 + r0) * BK + slotq;

    for (int it = 0; it < KIT; ++it) {
        load16_to_lds(pa,  dA);  pa  += BK;
        load16_to_lds(pb0, dB0); pb0 += BK;
        load16_to_lds(pb1, dB1); pb1 += BK;
        __syncthreads();

        int4 afp[2], bfp[4];
        #pragma unroll
        for (int mi = 0; mi < 2; ++mi)
            afp[mi] = *(const int4*)(&sA[aoff[mi]]);
        #pragma unroll
        for (int ni = 0; ni < 4; ++ni)
            bfp[ni] = *(const int4*)(&sB[boff[ni]]);
        __syncthreads();   // LDS free for next-iter staging during MFMAs

        #pragma unroll
        for (int mi = 0; mi < 2; ++mi)
            #pragma unroll
            for (int ni = 0; ni < 4; ++ni)
                acc[mi][ni] = __builtin_amdgcn_mfma_f32_16x16x32_fp8_fp8(lo64(afp[mi]), lo64(bfp[ni]), acc[mi][ni], 0, 0, 0);
        #pragma unroll
        for (int mi = 0; mi < 2; ++mi)
            #pragma unroll
            for (int ni = 0; ni < 4; ++ni)
                acc[mi][ni] = __builtin_amdgcn_mfma_f32_16x16x32_fp8_fp8(hi64(afp[mi]), hi64(bfp[ni]), acc[mi][ni], 0, 0, 0);
    }

    // ---- per-wave mask words (after K-loop: not live across it)
    unsigned qw[2]; int nq[2];
    #pragma unroll
    for (int t = 0; t < 2; ++t) {
        bool v = (lane < MQ) && (qm[(bBase + wr * 2 + t) * MQ + lane] != 0);
        unsigned long long bal = __ballot(v);
        qw[t] = (unsigned)bal;
        nq[t] = __popcll(bal);
    }
    unsigned pw[2]; int np_[2];
    #pragma unroll
    for (int t = 0; t < 2; ++t) {
        bool v = (lane < MP) && (pm[(pBase + wc * 2 + t) * MP + lane] != 0);
        unsigned long long bal = __ballot(v);
        pw[t] = (unsigned)bal;
        np_[t] = __popcll(bal);
    }

    // ---- selection: 4 pairs/wave, 10-bit fixed-point keys, ballot counting
    // C/D layout (m89): row=(lane>>4)*4+(t&3), col=(t>>2)*16+(lane&15)
    float aco = softplus_f(araw[0]);
    float bco = softplus_f(braw[0]);
    const int rowb = (lane >> 4) * 4;
    const int colb = lane & 15;

    #pragma unroll 1
    for (int pair = 0; pair < 4; ++pair) {
        f32x4 w0, w1; unsigned qwv, pwv; int nqv, npv;
        switch (pair) {   // static acc indexing (rule #20: no runtime index)
        case 0:  w0 = acc[0][0]; w1 = acc[0][1]; qwv = qw[0]; nqv = nq[0]; pwv = pw[0]; npv = np_[0]; break;
        case 1:  w0 = acc[0][2]; w1 = acc[0][3]; qwv = qw[0]; nqv = nq[0]; pwv = pw[1]; npv = np_[1]; break;
        case 2:  w0 = acc[1][0]; w1 = acc[1][1]; qwv = qw[1]; nqv = nq[1]; pwv = pw[0]; npv = np_[0]; break;
        default: w0 = acc[1][2]; w1 = acc[1][3]; qwv = qw[1]; nqv = nq[1]; pwv = pw[1]; npv = np_[1]; break;
        }

        int n  = nqv * npv;               // >= 1
        int k  = (4 * n) / 10; if (k < 1) k = 1;
        int m2 = n - (8 * n) / 10;        // complement rank, >= 1

        float v[8] = {w0[0], w0[1], w0[2], w0[3], w1[0], w1[1], w1[2], w1[3]};
        int key[8];
        float tot = 0.f;
        #pragma unroll
        for (int t = 0; t < 8; ++t) {
            int row = rowb + (t & 3);
            int col = (t >> 2) * 16 + colb;
            int kf = (int)floorf(v[t] * 2.0f) + 512;     // monotone, |v| << 256
            kf = min(max(kf, 1), 1023);                  // v_med3_i32
            bool val = (((qwv >> row) & 1u) != 0u) && (((pwv >> col) & 1u) != 0u);
            key[t] = val ? kf : 0;                       // valid >= 1
            if (val) tot += v[t];
        }

        // dual 10-bit MSB-first radix descent: ballot -> s_bcnt1_b64 on the
        // scalar pipe; thresholds stay wave-uniform, no DPP, no readlane.
        int T1 = 0, T2 = 0;
        for (int bit = 9; bit >= 0; --bit) {
            int c1 = T1 | (1 << bit);
            int c2 = T2 | (1 << bit);
            int cnt1 = 0, cnt2 = 0;
            #pragma unroll
            for (int t = 0; t < 8; ++t) {
                cnt1 += __popcll(__ballot(key[t] >= c1));
                cnt2 += __popcll(__ballot(key[t] >= c2));
            }
            if (cnt1 >= k)  T1 = c1;
            if (cnt2 >= m2) T2 = c2;
        }

        // tie-corrected sums: f32 via DPP (lane 63), counts via ballot (uniform)
        float S1 = 0.f, S2 = 0.f;
        int c1n = 0, c2n = 0;
        #pragma unroll
        for (int t = 0; t < 8; ++t) {
            bool g1 = key[t] > T1;
            bool g2 = key[t] > T2;
            if (g1) S1 += v[t];
            if (g2) S2 += v[t];
            c1n += __popcll(__ballot(g1));
            c2n += __popcll(__ballot(g2));
        }
        S1  = dpp_reduce_f32(S1);
        S2  = dpp_reduce_f32(S2);
        tot = dpp_reduce_f32(tot);

        if (lane == 63) {
            float f1 = 0.5f * (float)(T1 - 512);   // tie-bucket lower edge
            float f2 = 0.5f * (float)(T2 - 512);
            float top = S1 + (float)(k  - c1n) * f1;
            float cmp = S2 + (float)(m2 - c2n) * f2;
            float bot = tot - cmp;
            int bl = pair >> 1, pl = pair & 1;
            logits[(bBase + wr * 2 + bl) * PP + (pBase + wc * 2 + pl)] = aco * top - bco * bot;
        }
    }
}

// ---------- loss = mean_b (lse(logits[b,:]) - logits[b,b]) ----------
// 32 blocks x 4 waves, one row per wave, atomicAdd partials (out[0] zeroed
// by conv_fp8_both, stream-ordered).
__global__ __launch_bounds__(256) void loss_kernel(const float* __restrict__ logits,
                                                   float* __restrict__ loss_out) {
    const int lane = threadIdx.x & 63;
    const int wid  = threadIdx.x >> 6;
    const int r = blockIdx.x * 4 + wid;
    const float* row = logits + r * PP;
    float x0 = row[lane], x1 = row[lane + 64], x2 = row[lane + 128], x3 = row[lane + 192];
    float m = fmaxf(fmaxf(x0, x1), fmaxf(x2, x3));
    #pragma unroll
    for (int off = 32; off > 0; off >>= 1)
        m = fmaxf(m, __shfl_xor(m, off, 64));
    float s = expf(x0 - m) + expf(x1 - m) + expf(x2 - m) + expf(x3 - m);
    #pragma unroll
    for (int off = 32; off > 0; off >>= 1)
        s += __shfl_xor(s, off, 64);
    if (lane == 0)
        atomicAdd(loss_out, (m + logf(s) - row[r]) * (1.0f / (float)BQ));
}

extern "C" void kernel_launch(void* const* d_in, const int* in_sizes, int n_in,
                              void* d_out, int out_size, void* d_ws, size_t ws_size,
                              hipStream_t stream) {
    const float* q  = (const float*)d_in[0];
    const float* pe = (const float*)d_in[1];
    const int*   qm = (const int*)d_in[2];
    const int*   pm = (const int*)d_in[3];
    const float* ar = (const float*)d_in[4];
    const float* br = (const float*)d_in[5];
    float* out = (float*)d_out;           // [0] = loss, [1..32768] = logits

    // workspace: qb (1.5 MB fp8, k-shuffled) | pb (6 MB fp8, k-shuffled)
    char* ws = (char*)d_ws;
    unsigned char* qb = (unsigned char*)ws;
    unsigned char* pb = (unsigned char*)(ws + (size_t)MROWS * DD);

    // 1) convert fp32 -> fp8 e4m3 with k-shuffle (+ zero loss accumulator)
    conv_fp8_both<<<(NQG + NPG) / 256, 256, 0, stream>>>(
        (const float4*)q, (const float4*)pe, qb, pb, out);

    // 2) fused fp8 sim-GEMM + dual top-k -> logits
    // 12 KB LDS; (256,4) -> 128-reg budget, no spills, 4 blocks/CU,
    // grid 2048 = two clean uniform rounds
    dim3 gg(NROWS / BN, MROWS / BM, 1);   // (64, 32) = 2048 blocks
    gemm_select<<<gg, 256, 0, stream>>>(qb, pb, qm, pm, ar, br, out + 1);

    // 3) loss (parallel, atomic accumulate)
    loss_kernel<<<32, 256, 0, stream>>>(out + 1, out);
}